// Round 1
// baseline (3572.619 us; speedup 1.0000x reference)
//
#include <hip/hip_runtime.h>

#define N_NODES 200000
#define N_EDGES 6400000
#define F_IN 34
#define F_HID 10
#define F_OUT 4
#define HPAD 12   // pad h rows to 12 floats (48B) so rows are float4-aligned

// ws layout (floats):
//   [0,               N*HPAD)      h_pad  (x @ W_gcn, padded rows)
//   [N*HPAD,          N*HPAD+N)    deg    (float, includes self-loop)
//   [N*HPAD+N]                     mode flag (int: 0=int32 indices, 1=int64)

// ---------------------------------------------------------------- mode detect
// Reference produces int64 edge_index; harness doc says integers arrive as
// int32. Detect on-device: if the buffer is int64 (little-endian, values in
// [0,200000)), every odd 32-bit word is 0. 64 random int32 indices all being
// zero has probability ~0.
__global__ void detect_mode_kernel(const int* __restrict__ ei, int* __restrict__ mode) {
    int t = threadIdx.x;                 // 64 threads
    int v = ei[2 * t + 1];
    unsigned long long b = __ballot(v != 0);
    if (t == 0) *mode = (b == 0ull) ? 1 : 0;
}

// ---------------------------------------------------------------- init
// h = x @ W_gcn  (per-thread node, W staged in LDS); deg=1; zero hidden acc.
__global__ void init_kernel(const float* __restrict__ x,
                            const float* __restrict__ Wg,
                            float* __restrict__ hpad,
                            float* __restrict__ deg,
                            float* __restrict__ hidden /* d_out[0 : N*F_HID) */) {
    __shared__ float Ws[F_IN * F_HID];
    for (int t = threadIdx.x; t < F_IN * F_HID; t += blockDim.x) Ws[t] = Wg[t];
    __syncthreads();

    int i = blockIdx.x * blockDim.x + threadIdx.x;
    if (i >= N_NODES) return;

    float acc[F_HID];
#pragma unroll
    for (int f = 0; f < F_HID; ++f) acc[f] = 0.0f;

    const float* xr = x + (long long)i * F_IN;
#pragma unroll
    for (int k = 0; k < F_IN; ++k) {
        float xv = xr[k];
#pragma unroll
        for (int f = 0; f < F_HID; ++f) acc[f] += xv * Ws[k * F_HID + f];
    }

    float* hr = hpad + (long long)i * HPAD;
#pragma unroll
    for (int f = 0; f < F_HID; ++f) hr[f] = acc[f];
    hr[10] = 0.0f; hr[11] = 0.0f;

    deg[i] = 1.0f;  // self-loop

    float* hd = hidden + (long long)i * F_HID;
#pragma unroll
    for (int f = 0; f < F_HID; ++f) hd[f] = 0.0f;
}

// ---------------------------------------------------------------- degree
__global__ void deg_kernel(const int* __restrict__ ei,
                           const int* __restrict__ mode_p,
                           float* __restrict__ deg) {
    const int mode = *mode_p;
    long long stride = (long long)gridDim.x * blockDim.x;
    for (long long e = (long long)blockIdx.x * blockDim.x + threadIdx.x;
         e < N_EDGES; e += stride) {
        long long elem = (long long)N_EDGES + e;      // dst row
        int d = mode ? ei[2 * elem] : ei[elem];
        if ((unsigned)d < (unsigned)N_NODES) atomicAdd(&deg[d], 1.0f);
    }
}

// ---------------------------------------------------------------- scatter
__global__ void scatter_kernel(const int* __restrict__ ei,
                               const int* __restrict__ mode_p,
                               const float* __restrict__ hpad,
                               const float* __restrict__ deg,
                               float* __restrict__ hidden) {
    const int mode = *mode_p;
    long long e = (long long)blockIdx.x * blockDim.x + threadIdx.x;
    if (e >= N_EDGES) return;

    long long se = e;
    long long de = (long long)N_EDGES + e;
    int s = mode ? ei[2 * se] : ei[se];
    int d = mode ? ei[2 * de] : ei[de];
    if ((unsigned)s >= (unsigned)N_NODES || (unsigned)d >= (unsigned)N_NODES) return;

    float norm = rsqrtf(deg[s]) * rsqrtf(deg[d]);

    const float4* h4 = reinterpret_cast<const float4*>(hpad + (long long)s * HPAD);
    float4 a = h4[0];
    float4 b = h4[1];
    float4 c = h4[2];

    float* o = hidden + (long long)d * F_HID;
    atomicAdd(o + 0, a.x * norm);
    atomicAdd(o + 1, a.y * norm);
    atomicAdd(o + 2, a.z * norm);
    atomicAdd(o + 3, a.w * norm);
    atomicAdd(o + 4, b.x * norm);
    atomicAdd(o + 5, b.y * norm);
    atomicAdd(o + 6, b.z * norm);
    atomicAdd(o + 7, b.w * norm);
    atomicAdd(o + 8, c.x * norm);
    atomicAdd(o + 9, c.y * norm);
}

// ---------------------------------------------------------------- finalize
__global__ void finalize_kernel(const float* __restrict__ hpad,
                                const float* __restrict__ deg,
                                const float* __restrict__ b_gcn,
                                const float* __restrict__ W_fc,
                                const float* __restrict__ b_fc,
                                float* __restrict__ out) {
    __shared__ float Wf[F_HID * F_OUT];
    __shared__ float bf_s[F_OUT];
    __shared__ float bg_s[F_HID];
    for (int t = threadIdx.x; t < F_HID * F_OUT; t += blockDim.x) Wf[t] = W_fc[t];
    if (threadIdx.x < F_OUT) bf_s[threadIdx.x] = b_fc[threadIdx.x];
    if (threadIdx.x < F_HID) bg_s[threadIdx.x] = b_gcn[threadIdx.x];
    __syncthreads();

    int i = blockIdx.x * blockDim.x + threadIdx.x;
    if (i >= N_NODES) return;

    float* hidden = out;                                  // [N, F_HID]
    float* o2 = out + (long long)N_NODES * F_HID;         // [N, F_OUT]

    float inv = 1.0f / deg[i];                            // self-loop norm
    const float* hr = hpad + (long long)i * HPAD;
    float* hd = hidden + (long long)i * F_HID;

    float hv[F_HID];
#pragma unroll
    for (int f = 0; f < F_HID; ++f) {
        hv[f] = hd[f] + hr[f] * inv + bg_s[f];
        hd[f] = hv[f];
    }

#pragma unroll
    for (int j = 0; j < F_OUT; ++j) {
        float o = bf_s[j];
#pragma unroll
        for (int f = 0; f < F_HID; ++f) o += hv[f] * Wf[f * F_OUT + j];
        o2[(long long)i * F_OUT + j] = fmaxf(o, 0.0f);
    }
}

// ---------------------------------------------------------------- launch
extern "C" void kernel_launch(void* const* d_in, const int* in_sizes, int n_in,
                              void* d_out, int out_size, void* d_ws, size_t ws_size,
                              hipStream_t stream) {
    const float* x  = (const float*)d_in[0];
    const int*   ei = (const int*)d_in[1];
    const float* Wg = (const float*)d_in[2];
    const float* bg = (const float*)d_in[3];
    const float* Wf = (const float*)d_in[4];
    const float* bf = (const float*)d_in[5];
    float* out = (float*)d_out;

    float* hpad = (float*)d_ws;
    float* deg  = hpad + (size_t)N_NODES * HPAD;
    int*   mode = (int*)(deg + N_NODES);

    const int B = 256;
    detect_mode_kernel<<<1, 64, 0, stream>>>(ei, mode);
    init_kernel<<<(N_NODES + B - 1) / B, B, 0, stream>>>(x, Wg, hpad, deg, out);
    deg_kernel<<<2048, B, 0, stream>>>(ei, mode, deg);
    scatter_kernel<<<(N_EDGES + B - 1) / B, B, 0, stream>>>(ei, mode, hpad, deg, out);
    finalize_kernel<<<(N_NODES + B - 1) / B, B, 0, stream>>>(hpad, deg, bg, Wf, bf, out);
}

// Round 2
// 1083.979 us; speedup vs baseline: 3.2958x; 3.2958x over previous
//
#include <hip/hip_runtime.h>

#define N_NODES 200000
#define N_EDGES 6400000
#define F_IN 34
#define F_HID 10
#define F_OUT 4
#define HPAD 12                      // h rows padded to 12 floats; slot 10 = deg_inv_sqrt
#define NB_SCAN ((N_NODES + 255) / 256)   // 782 blocks for node-space scans

// ---------------------------------------------------------------- mode detect
// int64 edge_index => every odd 32-bit word is zero (values < 2^31).
__global__ void detect_mode_kernel(const int* __restrict__ ei, int* __restrict__ mode) {
    int t = threadIdx.x;                 // 64 threads
    int v = ei[2 * t + 1];
    unsigned long long b = __ballot(v != 0);
    if (t == 0) *mode = (b == 0ull) ? 1 : 0;
}

__device__ __forceinline__ int load_idx(const int* ei, long long elem, int mode) {
    return mode ? ei[2 * elem] : ei[elem];
}

// ================================================================ CSR PATH
// ---------------------------------------------------------------- init: h = x@W, deg_int = 0
__global__ void init_kernel(const float* __restrict__ x,
                            const float* __restrict__ Wg,
                            float* __restrict__ hpad,
                            int* __restrict__ deg_int) {
    __shared__ float Ws[F_IN * F_HID];
    for (int t = threadIdx.x; t < F_IN * F_HID; t += blockDim.x) Ws[t] = Wg[t];
    __syncthreads();

    int i = blockIdx.x * blockDim.x + threadIdx.x;
    if (i >= N_NODES) return;

    float acc[F_HID];
#pragma unroll
    for (int f = 0; f < F_HID; ++f) acc[f] = 0.0f;

    const float* xr = x + (long long)i * F_IN;
#pragma unroll
    for (int k = 0; k < F_IN; ++k) {
        float xv = xr[k];
#pragma unroll
        for (int f = 0; f < F_HID; ++f) acc[f] += xv * Ws[k * F_HID + f];
    }

    float* hr = hpad + (long long)i * HPAD;
#pragma unroll
    for (int f = 0; f < F_HID; ++f) hr[f] = acc[f];
    hr[10] = 0.0f; hr[11] = 0.0f;

    deg_int[i] = 0;
}

// ---------------------------------------------------------------- histogram over dst
__global__ void hist_kernel(const int* __restrict__ ei,
                            const int* __restrict__ mode_p,
                            int* __restrict__ deg_int) {
    const int mode = *mode_p;
    long long e = (long long)blockIdx.x * blockDim.x + threadIdx.x;
    if (e >= N_EDGES) return;
    int d = load_idx(ei, (long long)N_EDGES + e, mode);
    if ((unsigned)d < (unsigned)N_NODES) atomicAdd(&deg_int[d], 1);
}

// ---------------------------------------------------------------- scan A: per-block sums
__global__ void scanA_kernel(const int* __restrict__ deg_int, int* __restrict__ bsum) {
    __shared__ int s[256];
    int t = threadIdx.x;
    int i = blockIdx.x * 256 + t;
    s[t] = (i < N_NODES) ? deg_int[i] : 0;
    __syncthreads();
    for (int o = 128; o > 0; o >>= 1) {
        if (t < o) s[t] += s[t + o];
        __syncthreads();
    }
    if (t == 0) bsum[blockIdx.x] = s[0];
}

// ---------------------------------------------------------------- scan B: exclusive scan of block sums
__global__ void scanB_kernel(int* __restrict__ bsum, int* __restrict__ rowptr) {
    __shared__ int s[1024];
    int t = threadIdx.x;
    int v = (t < NB_SCAN) ? bsum[t] : 0;
    s[t] = v;
    __syncthreads();
    for (int o = 1; o < 1024; o <<= 1) {
        int u = (t >= o) ? s[t - o] : 0;
        __syncthreads();
        s[t] += u;
        __syncthreads();
    }
    if (t < NB_SCAN) bsum[t] = s[t] - v;               // exclusive block offset
    if (t == NB_SCAN - 1) rowptr[N_NODES] = s[t];      // total valid edges
}

// ---------------------------------------------------------------- scan C: rowptr/cursor/dis
__global__ void scanC_kernel(const int* __restrict__ deg_int,
                             const int* __restrict__ bsum,
                             int* __restrict__ rowptr,
                             int* __restrict__ cursor,
                             float* __restrict__ hpad) {
    __shared__ int s[256];
    int t = threadIdx.x;
    int i = blockIdx.x * 256 + t;
    int v = (i < N_NODES) ? deg_int[i] : 0;
    s[t] = v;
    __syncthreads();
    for (int o = 1; o < 256; o <<= 1) {
        int u = (t >= o) ? s[t - o] : 0;
        __syncthreads();
        s[t] += u;
        __syncthreads();
    }
    if (i < N_NODES) {
        int off = bsum[blockIdx.x] + s[t] - v;         // exclusive prefix
        rowptr[i] = off;
        cursor[i] = off;
        hpad[(long long)i * HPAD + 10] = rsqrtf((float)(v + 1));  // +1 self-loop
    }
}

// ---------------------------------------------------------------- fill CSR
__global__ void fill_kernel(const int* __restrict__ ei,
                            const int* __restrict__ mode_p,
                            int* __restrict__ cursor,
                            int* __restrict__ csr) {
    const int mode = *mode_p;
    long long e = (long long)blockIdx.x * blockDim.x + threadIdx.x;
    if (e >= N_EDGES) return;
    int s = load_idx(ei, e, mode);
    int d = load_idx(ei, (long long)N_EDGES + e, mode);
    if ((unsigned)s >= (unsigned)N_NODES || (unsigned)d >= (unsigned)N_NODES) return;
    int pos = atomicAdd(&cursor[d], 1);
    csr[pos] = s;
}

// ---------------------------------------------------------------- gather + epilogue
__global__ void gather_kernel(const int* __restrict__ csr,
                              const int* __restrict__ rowptr,
                              const float* __restrict__ hpad,
                              const float* __restrict__ b_gcn,
                              const float* __restrict__ W_fc,
                              const float* __restrict__ b_fc,
                              float* __restrict__ out) {
    __shared__ float Wfs[F_HID * F_OUT];
    __shared__ float bfs[F_OUT];
    __shared__ float bgs[F_HID];
    for (int t = threadIdx.x; t < F_HID * F_OUT; t += blockDim.x) Wfs[t] = W_fc[t];
    if (threadIdx.x < F_OUT) bfs[threadIdx.x] = b_fc[threadIdx.x];
    if (threadIdx.x < F_HID) bgs[threadIdx.x] = b_gcn[threadIdx.x];
    __syncthreads();

    int i = blockIdx.x * blockDim.x + threadIdx.x;
    if (i >= N_NODES) return;

    const float4* h4 = reinterpret_cast<const float4*>(hpad);
    float4 f0 = h4[(long long)i * 3 + 0];
    float4 f1 = h4[(long long)i * 3 + 1];
    float4 f2 = h4[(long long)i * 3 + 2];
    float di = f2.z;                                  // deg_inv_sqrt[i]

    float acc[F_HID];
    acc[0] = f0.x * di; acc[1] = f0.y * di; acc[2] = f0.z * di; acc[3] = f0.w * di;
    acc[4] = f1.x * di; acc[5] = f1.y * di; acc[6] = f1.z * di; acc[7] = f1.w * di;
    acc[8] = f2.x * di; acc[9] = f2.y * di;           // self-loop term (× di again below)

    int rs = rowptr[i];
    int re = rowptr[i + 1];
    for (int e = rs; e < re; ++e) {
        int s = csr[e];
        float4 g0 = h4[(long long)s * 3 + 0];
        float4 g1 = h4[(long long)s * 3 + 1];
        float4 g2 = h4[(long long)s * 3 + 2];
        float w = g2.z;                               // deg_inv_sqrt[s]
        acc[0] += g0.x * w; acc[1] += g0.y * w; acc[2] += g0.z * w; acc[3] += g0.w * w;
        acc[4] += g1.x * w; acc[5] += g1.y * w; acc[6] += g1.z * w; acc[7] += g1.w * w;
        acc[8] += g2.x * w; acc[9] += g2.y * w;
    }

    float hv[F_HID];
    float* hidden = out;                               // [N, F_HID]
    float* o2 = out + (long long)N_NODES * F_HID;      // [N, F_OUT]
#pragma unroll
    for (int f = 0; f < F_HID; ++f) {
        hv[f] = acc[f] * di + bgs[f];
        hidden[(long long)i * F_HID + f] = hv[f];
    }
#pragma unroll
    for (int j = 0; j < F_OUT; ++j) {
        float o = bfs[j];
#pragma unroll
        for (int f = 0; f < F_HID; ++f) o += hv[f] * Wfs[f * F_OUT + j];
        o2[(long long)i * F_OUT + j] = fmaxf(o, 0.0f);
    }
}

// ================================================================ FALLBACK (round-1 scatter) —
// used only if ws_size can't hold the CSR. Deterministic host-side branch.
__global__ void fb_init_kernel(const float* __restrict__ x,
                               const float* __restrict__ Wg,
                               float* __restrict__ hpad,
                               float* __restrict__ deg,
                               float* __restrict__ hidden) {
    __shared__ float Ws[F_IN * F_HID];
    for (int t = threadIdx.x; t < F_IN * F_HID; t += blockDim.x) Ws[t] = Wg[t];
    __syncthreads();
    int i = blockIdx.x * blockDim.x + threadIdx.x;
    if (i >= N_NODES) return;
    float acc[F_HID];
#pragma unroll
    for (int f = 0; f < F_HID; ++f) acc[f] = 0.0f;
    const float* xr = x + (long long)i * F_IN;
#pragma unroll
    for (int k = 0; k < F_IN; ++k) {
        float xv = xr[k];
#pragma unroll
        for (int f = 0; f < F_HID; ++f) acc[f] += xv * Ws[k * F_HID + f];
    }
    float* hr = hpad + (long long)i * HPAD;
#pragma unroll
    for (int f = 0; f < F_HID; ++f) hr[f] = acc[f];
    hr[10] = 0.0f; hr[11] = 0.0f;
    deg[i] = 1.0f;
    float* hd = hidden + (long long)i * F_HID;
#pragma unroll
    for (int f = 0; f < F_HID; ++f) hd[f] = 0.0f;
}

__global__ void fb_deg_kernel(const int* __restrict__ ei, const int* __restrict__ mode_p,
                              float* __restrict__ deg) {
    const int mode = *mode_p;
    long long e = (long long)blockIdx.x * blockDim.x + threadIdx.x;
    if (e >= N_EDGES) return;
    int d = load_idx(ei, (long long)N_EDGES + e, mode);
    if ((unsigned)d < (unsigned)N_NODES) atomicAdd(&deg[d], 1.0f);
}

__global__ void fb_scatter_kernel(const int* __restrict__ ei, const int* __restrict__ mode_p,
                                  const float* __restrict__ hpad, const float* __restrict__ deg,
                                  float* __restrict__ hidden) {
    const int mode = *mode_p;
    long long e = (long long)blockIdx.x * blockDim.x + threadIdx.x;
    if (e >= N_EDGES) return;
    int s = load_idx(ei, e, mode);
    int d = load_idx(ei, (long long)N_EDGES + e, mode);
    if ((unsigned)s >= (unsigned)N_NODES || (unsigned)d >= (unsigned)N_NODES) return;
    float norm = rsqrtf(deg[s]) * rsqrtf(deg[d]);
    const float4* h4 = reinterpret_cast<const float4*>(hpad + (long long)s * HPAD);
    float4 a = h4[0]; float4 b = h4[1]; float4 c = h4[2];
    float* o = hidden + (long long)d * F_HID;
    atomicAdd(o + 0, a.x * norm); atomicAdd(o + 1, a.y * norm);
    atomicAdd(o + 2, a.z * norm); atomicAdd(o + 3, a.w * norm);
    atomicAdd(o + 4, b.x * norm); atomicAdd(o + 5, b.y * norm);
    atomicAdd(o + 6, b.z * norm); atomicAdd(o + 7, b.w * norm);
    atomicAdd(o + 8, c.x * norm); atomicAdd(o + 9, c.y * norm);
}

__global__ void fb_finalize_kernel(const float* __restrict__ hpad, const float* __restrict__ deg,
                                   const float* __restrict__ b_gcn, const float* __restrict__ W_fc,
                                   const float* __restrict__ b_fc, float* __restrict__ out) {
    __shared__ float Wf[F_HID * F_OUT];
    __shared__ float bf_s[F_OUT];
    __shared__ float bg_s[F_HID];
    for (int t = threadIdx.x; t < F_HID * F_OUT; t += blockDim.x) Wf[t] = W_fc[t];
    if (threadIdx.x < F_OUT) bf_s[threadIdx.x] = b_fc[threadIdx.x];
    if (threadIdx.x < F_HID) bg_s[threadIdx.x] = b_gcn[threadIdx.x];
    __syncthreads();
    int i = blockIdx.x * blockDim.x + threadIdx.x;
    if (i >= N_NODES) return;
    float* hidden = out;
    float* o2 = out + (long long)N_NODES * F_HID;
    float inv = 1.0f / deg[i];
    const float* hr = hpad + (long long)i * HPAD;
    float* hd = hidden + (long long)i * F_HID;
    float hv[F_HID];
#pragma unroll
    for (int f = 0; f < F_HID; ++f) {
        hv[f] = hd[f] + hr[f] * inv + bg_s[f];
        hd[f] = hv[f];
    }
#pragma unroll
    for (int j = 0; j < F_OUT; ++j) {
        float o = bf_s[j];
#pragma unroll
        for (int f = 0; f < F_HID; ++f) o += hv[f] * Wf[f * F_OUT + j];
        o2[(long long)i * F_OUT + j] = fmaxf(o, 0.0f);
    }
}

// ---------------------------------------------------------------- launch
extern "C" void kernel_launch(void* const* d_in, const int* in_sizes, int n_in,
                              void* d_out, int out_size, void* d_ws, size_t ws_size,
                              hipStream_t stream) {
    const float* x  = (const float*)d_in[0];
    const int*   ei = (const int*)d_in[1];
    const float* Wg = (const float*)d_in[2];
    const float* bg = (const float*)d_in[3];
    const float* Wf = (const float*)d_in[4];
    const float* bf = (const float*)d_in[5];
    float* out = (float*)d_out;

    const int B = 256;
    const int nblk_node = (N_NODES + B - 1) / B;     // 782
    const int nblk_edge = (N_EDGES + B - 1) / B;     // 25000

    // CSR layout in ws
    float* hpad   = (float*)d_ws;                                  // N*HPAD floats
    int*   deg_i  = (int*)(hpad + (size_t)N_NODES * HPAD);         // N
    int*   rowptr = deg_i + N_NODES;                               // N+1
    int*   cursor = rowptr + N_NODES + 1;                          // N
    int*   bsum   = cursor + N_NODES;                              // 1024
    int*   csr    = bsum + 1024;                                   // N_EDGES
    int*   mode   = csr + N_EDGES;                                 // 1
    size_t need_bytes = (size_t)((char*)(mode + 1) - (char*)d_ws);

    if (ws_size >= need_bytes) {
        detect_mode_kernel<<<1, 64, 0, stream>>>(ei, mode);
        init_kernel<<<nblk_node, B, 0, stream>>>(x, Wg, hpad, deg_i);
        hist_kernel<<<nblk_edge, B, 0, stream>>>(ei, mode, deg_i);
        scanA_kernel<<<NB_SCAN, 256, 0, stream>>>(deg_i, bsum);
        scanB_kernel<<<1, 1024, 0, stream>>>(bsum, rowptr);
        scanC_kernel<<<NB_SCAN, 256, 0, stream>>>(deg_i, bsum, rowptr, cursor, hpad);
        fill_kernel<<<nblk_edge, B, 0, stream>>>(ei, mode, cursor, csr);
        gather_kernel<<<nblk_node, B, 0, stream>>>(csr, rowptr, hpad, bg, Wf, bf, out);
    } else {
        // fallback: round-1 atomic scatter (needs only ~10.4 MB)
        float* degf  = hpad + (size_t)N_NODES * HPAD;
        int*   mode2 = (int*)(degf + N_NODES);
        detect_mode_kernel<<<1, 64, 0, stream>>>(ei, mode2);
        fb_init_kernel<<<nblk_node, B, 0, stream>>>(x, Wg, hpad, degf, out);
        fb_deg_kernel<<<nblk_edge, B, 0, stream>>>(ei, mode2, degf);
        fb_scatter_kernel<<<nblk_edge, B, 0, stream>>>(ei, mode2, hpad, degf, out);
        fb_finalize_kernel<<<nblk_node, B, 0, stream>>>(hpad, degf, bg, Wf, bf, out);
    }
}

// Round 3
// 457.604 us; speedup vs baseline: 7.8072x; 2.3688x over previous
//
#include <hip/hip_runtime.h>

#define N_NODES 200000
#define N_EDGES 6400000
#define F_IN 34
#define F_HID 10
#define F_OUT 4
#define HPAD 12              // h rows: 10 feats, slot10 = deg_inv_sqrt, slot11 pad
#define BINS 256
#define NPB 782              // nodes per bin: 256*782 = 200192 >= N_NODES
#define CHUNK 8192
#define BLK1 ((N_EDGES + CHUNK - 1) / CHUNK)   // 782 edge-chunk blocks
#define SCAN_L (BINS * BLK1)                    // 200192 = 782*256 exactly
#define ACCP 11              // LDS acc padding: gcd(11,32)=1 -> all banks

// ---------------------------------------------------------------- mode detect
__global__ void detect_mode_kernel(const int* __restrict__ ei, int* __restrict__ mode) {
    int t = threadIdx.x;                 // 64 threads
    int v = ei[2 * t + 1];
    unsigned long long b = __ballot(v != 0);
    if (t == 0) *mode = (b == 0ull) ? 1 : 0;
}

__device__ __forceinline__ int load_idx(const int* ei, long long elem, int mode) {
    return mode ? ei[2 * elem] : ei[elem];
}

// ---------------------------------------------------------------- init: h = x @ W
__global__ void init_kernel(const float* __restrict__ x,
                            const float* __restrict__ Wg,
                            float* __restrict__ hpad) {
    __shared__ float Ws[F_IN * F_HID];
    for (int t = threadIdx.x; t < F_IN * F_HID; t += blockDim.x) Ws[t] = Wg[t];
    __syncthreads();

    int i = blockIdx.x * blockDim.x + threadIdx.x;
    if (i >= N_NODES) return;

    float acc[F_HID];
#pragma unroll
    for (int f = 0; f < F_HID; ++f) acc[f] = 0.0f;

    const float* xr = x + (long long)i * F_IN;
#pragma unroll
    for (int k = 0; k < F_IN; ++k) {
        float xv = xr[k];
#pragma unroll
        for (int f = 0; f < F_HID; ++f) acc[f] += xv * Ws[k * F_HID + f];
    }

    float* hr = hpad + (long long)i * HPAD;
#pragma unroll
    for (int f = 0; f < F_HID; ++f) hr[f] = acc[f];
    hr[10] = 0.0f; hr[11] = 0.0f;
}

// ---------------------------------------------------------------- pass 1: bucket counts (LDS hist)
__global__ void p1_count_kernel(const int* __restrict__ ei,
                                const int* __restrict__ mode_p,
                                int* __restrict__ bcnt) {
    __shared__ int hist[BINS];
    const int mode = *mode_p;
    int t = threadIdx.x;
    if (t < BINS) hist[t] = 0;
    __syncthreads();

    long long base = (long long)blockIdx.x * CHUNK;
    for (int k = t; k < CHUNK; k += blockDim.x) {
        long long e = base + k;
        if (e >= N_EDGES) break;
        int d = load_idx(ei, (long long)N_EDGES + e, mode);
        if ((unsigned)d < (unsigned)N_NODES) atomicAdd(&hist[d / NPB], 1);
    }
    __syncthreads();
    if (t < BINS) bcnt[t * BLK1 + blockIdx.x] = hist[t];   // bin-major
}

// ---------------------------------------------------------------- scan A: per-block sums
__global__ void scanA_kernel(const int* __restrict__ src, int* __restrict__ bsum) {
    __shared__ int s[256];
    int t = threadIdx.x;
    int i = blockIdx.x * 256 + t;
    s[t] = (i < SCAN_L) ? src[i] : 0;
    __syncthreads();
    for (int o = 128; o > 0; o >>= 1) {
        if (t < o) s[t] += s[t + o];
        __syncthreads();
    }
    if (t == 0) bsum[blockIdx.x] = s[0];
}

// ---------------------------------------------------------------- scan B: exclusive scan of block sums
__global__ void scanB_kernel(int* __restrict__ bsum, int* __restrict__ total) {
    __shared__ int s[1024];
    int t = threadIdx.x;
    int v = (t < BLK1) ? bsum[t] : 0;
    s[t] = v;
    __syncthreads();
    for (int o = 1; o < 1024; o <<= 1) {
        int u = (t >= o) ? s[t - o] : 0;
        __syncthreads();
        s[t] += u;
        __syncthreads();
    }
    if (t < BLK1) bsum[t] = s[t] - v;           // exclusive block offset
    if (t == 1023) *total = s[t];
}

// ---------------------------------------------------------------- scan C: produce boff
__global__ void scanC_kernel(const int* __restrict__ src,
                             const int* __restrict__ bsum,
                             int* __restrict__ dst) {
    __shared__ int s[256];
    int t = threadIdx.x;
    int i = blockIdx.x * 256 + t;
    int v = (i < SCAN_L) ? src[i] : 0;
    s[t] = v;
    __syncthreads();
    for (int o = 1; o < 256; o <<= 1) {
        int u = (t >= o) ? s[t - o] : 0;
        __syncthreads();
        s[t] += u;
        __syncthreads();
    }
    if (i < SCAN_L) dst[i] = bsum[blockIdx.x] + s[t] - v;  // exclusive prefix
}

// ---------------------------------------------------------------- pass 3: bucket fill (LDS cursors)
__global__ void p3_fill_kernel(const int* __restrict__ ei,
                               const int* __restrict__ mode_p,
                               const int* __restrict__ boff,
                               int* __restrict__ ebuf) {
    __shared__ int cur[BINS];
    const int mode = *mode_p;
    int t = threadIdx.x;
    if (t < BINS) cur[t] = boff[t * BLK1 + blockIdx.x];
    __syncthreads();

    long long base = (long long)blockIdx.x * CHUNK;
    for (int k = t; k < CHUNK; k += blockDim.x) {
        long long e = base + k;
        if (e >= N_EDGES) break;
        int d = load_idx(ei, (long long)N_EDGES + e, mode);
        if ((unsigned)d >= (unsigned)N_NODES) continue;
        int s = load_idx(ei, e, mode);
        int bin = d / NPB;
        int ld = d - bin * NPB;
        int pos = atomicAdd(&cur[bin], 1);
        ebuf[pos] = s | (ld << 18);              // src:18 bits | local_dst:10 bits
    }
}

// ---------------------------------------------------------------- pass 4a: per-node degree -> dis
__global__ void p4a_deg_kernel(const int* __restrict__ ebuf,
                               const int* __restrict__ boff,
                               const int* __restrict__ total,
                               float* __restrict__ hpad) {
    __shared__ int cnt[NPB];
    int b = blockIdx.x;
    int t = threadIdx.x;
    for (int j = t; j < NPB; j += blockDim.x) cnt[j] = 0;
    __syncthreads();

    int start = boff[b * BLK1];
    int end = (b < BINS - 1) ? boff[(b + 1) * BLK1] : *total;
    for (int e = start + t; e < end; e += blockDim.x)
        atomicAdd(&cnt[((unsigned)ebuf[e]) >> 18], 1);
    __syncthreads();

    for (int j = t; j < NPB; j += blockDim.x) {
        int i = b * NPB + j;
        if (i < N_NODES)
            hpad[(long long)i * HPAD + 10] = rsqrtf((float)(cnt[j] + 1));  // +1 self-loop
    }
}

// ---------------------------------------------------------------- pass 4b: accumulate + epilogue
__global__ void p4b_acc_kernel(const int* __restrict__ ebuf,
                               const int* __restrict__ boff,
                               const int* __restrict__ total,
                               const float* __restrict__ hpad,
                               const float* __restrict__ b_gcn,
                               const float* __restrict__ W_fc,
                               const float* __restrict__ b_fc,
                               float* __restrict__ out) {
    __shared__ float accs[NPB * ACCP];
    __shared__ float disL[NPB];
    __shared__ float Wfs[F_HID * F_OUT];
    __shared__ float bfs[F_OUT];
    __shared__ float bgs[F_HID];

    int b = blockIdx.x;
    int t = threadIdx.x;

    for (int j = t; j < NPB * ACCP; j += blockDim.x) accs[j] = 0.0f;
    for (int j = t; j < NPB; j += blockDim.x) {
        int i = b * NPB + j;
        disL[j] = (i < N_NODES) ? hpad[(long long)i * HPAD + 10] : 0.0f;
    }
    if (t < F_HID * F_OUT) Wfs[t] = W_fc[t];
    if (t < F_OUT) bfs[t] = b_fc[t];
    if (t < F_HID) bgs[t] = b_gcn[t];
    __syncthreads();

    const float4* h4 = reinterpret_cast<const float4*>(hpad);
    int start = boff[b * BLK1];
    int end = (b < BINS - 1) ? boff[(b + 1) * BLK1] : *total;

    for (int e = start + t; e < end; e += blockDim.x) {
        unsigned v = (unsigned)ebuf[e];
        int s = v & 0x3FFFF;
        int ld = v >> 18;
        float4 g0 = h4[(long long)s * 3 + 0];
        float4 g1 = h4[(long long)s * 3 + 1];
        float4 g2 = h4[(long long)s * 3 + 2];
        float w = g2.z;                          // dis[src]
        float* a = &accs[ld * ACCP];
        atomicAdd(a + 0, g0.x * w); atomicAdd(a + 1, g0.y * w);
        atomicAdd(a + 2, g0.z * w); atomicAdd(a + 3, g0.w * w);
        atomicAdd(a + 4, g1.x * w); atomicAdd(a + 5, g1.y * w);
        atomicAdd(a + 6, g1.z * w); atomicAdd(a + 7, g1.w * w);
        atomicAdd(a + 8, g2.x * w); atomicAdd(a + 9, g2.y * w);
    }
    __syncthreads();

    float* hidden = out;                               // [N, F_HID]
    float4* o24 = reinterpret_cast<float4*>(out + (long long)N_NODES * F_HID);

    for (int j = t; j < NPB; j += blockDim.x) {
        int i = b * NPB + j;
        if (i >= N_NODES) continue;
        float di = disL[j];
        float4 f0 = h4[(long long)i * 3 + 0];
        float4 f1 = h4[(long long)i * 3 + 1];
        float4 f2 = h4[(long long)i * 3 + 2];
        float hs[F_HID] = {f0.x, f0.y, f0.z, f0.w, f1.x, f1.y, f1.z, f1.w, f2.x, f2.y};

        float hv[F_HID];
#pragma unroll
        for (int f = 0; f < F_HID; ++f) {
            hv[f] = (accs[j * ACCP + f] + hs[f] * di) * di + bgs[f];
            hidden[(long long)i * F_HID + f] = hv[f];
        }
        float4 o;
        float* op = &o.x;
#pragma unroll
        for (int jj = 0; jj < F_OUT; ++jj) {
            float v = bfs[jj];
#pragma unroll
            for (int f = 0; f < F_HID; ++f) v += hv[f] * Wfs[f * F_OUT + jj];
            op[jj] = fmaxf(v, 0.0f);
        }
        o24[i] = o;
    }
}

// ================================================================ FALLBACK (atomic scatter)
__global__ void fb_init_kernel(const float* __restrict__ x, const float* __restrict__ Wg,
                               float* __restrict__ hpad, float* __restrict__ deg,
                               float* __restrict__ hidden) {
    __shared__ float Ws[F_IN * F_HID];
    for (int t = threadIdx.x; t < F_IN * F_HID; t += blockDim.x) Ws[t] = Wg[t];
    __syncthreads();
    int i = blockIdx.x * blockDim.x + threadIdx.x;
    if (i >= N_NODES) return;
    float acc[F_HID];
#pragma unroll
    for (int f = 0; f < F_HID; ++f) acc[f] = 0.0f;
    const float* xr = x + (long long)i * F_IN;
#pragma unroll
    for (int k = 0; k < F_IN; ++k) {
        float xv = xr[k];
#pragma unroll
        for (int f = 0; f < F_HID; ++f) acc[f] += xv * Ws[k * F_HID + f];
    }
    float* hr = hpad + (long long)i * HPAD;
#pragma unroll
    for (int f = 0; f < F_HID; ++f) hr[f] = acc[f];
    hr[10] = 0.0f; hr[11] = 0.0f;
    deg[i] = 1.0f;
    float* hd = hidden + (long long)i * F_HID;
#pragma unroll
    for (int f = 0; f < F_HID; ++f) hd[f] = 0.0f;
}

__global__ void fb_deg_kernel(const int* __restrict__ ei, const int* __restrict__ mode_p,
                              float* __restrict__ deg) {
    const int mode = *mode_p;
    long long e = (long long)blockIdx.x * blockDim.x + threadIdx.x;
    if (e >= N_EDGES) return;
    int d = load_idx(ei, (long long)N_EDGES + e, mode);
    if ((unsigned)d < (unsigned)N_NODES) atomicAdd(&deg[d], 1.0f);
}

__global__ void fb_scatter_kernel(const int* __restrict__ ei, const int* __restrict__ mode_p,
                                  const float* __restrict__ hpad, const float* __restrict__ deg,
                                  float* __restrict__ hidden) {
    const int mode = *mode_p;
    long long e = (long long)blockIdx.x * blockDim.x + threadIdx.x;
    if (e >= N_EDGES) return;
    int s = load_idx(ei, e, mode);
    int d = load_idx(ei, (long long)N_EDGES + e, mode);
    if ((unsigned)s >= (unsigned)N_NODES || (unsigned)d >= (unsigned)N_NODES) return;
    float norm = rsqrtf(deg[s]) * rsqrtf(deg[d]);
    const float4* h4 = reinterpret_cast<const float4*>(hpad + (long long)s * HPAD);
    float4 a = h4[0]; float4 b = h4[1]; float4 c = h4[2];
    float* o = hidden + (long long)d * F_HID;
    atomicAdd(o + 0, a.x * norm); atomicAdd(o + 1, a.y * norm);
    atomicAdd(o + 2, a.z * norm); atomicAdd(o + 3, a.w * norm);
    atomicAdd(o + 4, b.x * norm); atomicAdd(o + 5, b.y * norm);
    atomicAdd(o + 6, b.z * norm); atomicAdd(o + 7, b.w * norm);
    atomicAdd(o + 8, c.x * norm); atomicAdd(o + 9, c.y * norm);
}

__global__ void fb_finalize_kernel(const float* __restrict__ hpad, const float* __restrict__ deg,
                                   const float* __restrict__ b_gcn, const float* __restrict__ W_fc,
                                   const float* __restrict__ b_fc, float* __restrict__ out) {
    __shared__ float Wf[F_HID * F_OUT];
    __shared__ float bf_s[F_OUT];
    __shared__ float bg_s[F_HID];
    for (int t = threadIdx.x; t < F_HID * F_OUT; t += blockDim.x) Wf[t] = W_fc[t];
    if (threadIdx.x < F_OUT) bf_s[threadIdx.x] = b_fc[threadIdx.x];
    if (threadIdx.x < F_HID) bg_s[threadIdx.x] = b_gcn[threadIdx.x];
    __syncthreads();
    int i = blockIdx.x * blockDim.x + threadIdx.x;
    if (i >= N_NODES) return;
    float* hidden = out;
    float* o2 = out + (long long)N_NODES * F_HID;
    float inv = 1.0f / deg[i];
    const float* hr = hpad + (long long)i * HPAD;
    float* hd = hidden + (long long)i * F_HID;
    float hv[F_HID];
#pragma unroll
    for (int f = 0; f < F_HID; ++f) {
        hv[f] = hd[f] + hr[f] * inv + bg_s[f];
        hd[f] = hv[f];
    }
#pragma unroll
    for (int j = 0; j < F_OUT; ++j) {
        float o = bf_s[j];
#pragma unroll
        for (int f = 0; f < F_HID; ++f) o += hv[f] * Wf[f * F_OUT + j];
        o2[(long long)i * F_OUT + j] = fmaxf(o, 0.0f);
    }
}

// ---------------------------------------------------------------- launch
extern "C" void kernel_launch(void* const* d_in, const int* in_sizes, int n_in,
                              void* d_out, int out_size, void* d_ws, size_t ws_size,
                              hipStream_t stream) {
    const float* x  = (const float*)d_in[0];
    const int*   ei = (const int*)d_in[1];
    const float* Wg = (const float*)d_in[2];
    const float* bg = (const float*)d_in[3];
    const float* Wf = (const float*)d_in[4];
    const float* bf = (const float*)d_in[5];
    float* out = (float*)d_out;

    const int B = 256;
    const int nblk_node = (N_NODES + B - 1) / B;     // 782

    // sort-path ws layout
    float* hpad  = (float*)d_ws;                               // N*HPAD
    int*   bcnt  = (int*)(hpad + (size_t)N_NODES * HPAD);      // SCAN_L
    int*   boff  = bcnt + SCAN_L;                              // SCAN_L
    int*   bsum  = boff + SCAN_L;                              // 1024
    int*   total = bsum + 1024;                                // 1
    int*   ebuf  = total + 1;                                  // N_EDGES
    int*   mode  = ebuf + N_EDGES;                             // 1
    size_t need = (size_t)((char*)(mode + 1) - (char*)d_ws);

    if (ws_size >= need) {
        detect_mode_kernel<<<1, 64, 0, stream>>>(ei, mode);
        init_kernel<<<nblk_node, B, 0, stream>>>(x, Wg, hpad);
        p1_count_kernel<<<BLK1, B, 0, stream>>>(ei, mode, bcnt);
        scanA_kernel<<<(SCAN_L + 255) / 256, 256, 0, stream>>>(bcnt, bsum);
        scanB_kernel<<<1, 1024, 0, stream>>>(bsum, total);
        scanC_kernel<<<(SCAN_L + 255) / 256, 256, 0, stream>>>(bcnt, bsum, boff);
        p3_fill_kernel<<<BLK1, B, 0, stream>>>(ei, mode, boff, ebuf);
        p4a_deg_kernel<<<BINS, 256, 0, stream>>>(ebuf, boff, total, hpad);
        p4b_acc_kernel<<<BINS, 1024, 0, stream>>>(ebuf, boff, total, hpad, bg, Wf, bf, out);
    } else {
        // fallback: atomic scatter (~10.4 MB)
        float* degf  = hpad + (size_t)N_NODES * HPAD;
        int*   mode2 = (int*)(degf + N_NODES);
        const int nblk_edge = (N_EDGES + B - 1) / B;
        detect_mode_kernel<<<1, 64, 0, stream>>>(ei, mode2);
        fb_init_kernel<<<nblk_node, B, 0, stream>>>(x, Wg, hpad, degf, out);
        fb_deg_kernel<<<nblk_edge, B, 0, stream>>>(ei, mode2, degf);
        fb_scatter_kernel<<<nblk_edge, B, 0, stream>>>(ei, mode2, hpad, degf, out);
        fb_finalize_kernel<<<nblk_node, B, 0, stream>>>(hpad, degf, bg, Wf, bf, out);
    }
}